// Round 4
// baseline (373.307 us; speedup 1.0000x reference)
//
#include <hip/hip_runtime.h>

// ============================================================================
// MoR block: depth router + token top-k + RMSNorm + causal MHA + ACM gate +
// SwiGLU MLP.  B=2 S=2048 D=768 H=12 Dh=64 F=2048.
// Outputs (f32, concat): hidden[2,2048,768] | depth_probs[2,2048] | mask[2,2048]
// Round 4: attention restructure. QBLK=128 (4 waves x 32 q-rows), V fed from a
// pre-transposed vT (new k_transpose_bf, aliases normed), XOR-swizzled K/V LDS
// tiles, exp2-domain softmax, boundary-only causal masking, reg prefetch of
// next K/V tile, heavy-tile-first dispatch.  (Round-3 attn: 112us, MfmaUtil
// 4.5%, 9.3M LDS conflict cycles.)
// ============================================================================

typedef float f32x4 __attribute__((ext_vector_type(4)));
typedef __bf16 bf16x8 __attribute__((ext_vector_type(8)));
typedef unsigned int u32;

#define DEV static __device__ __forceinline__

constexpr int SEQ = 2048, DIM = 768, NH = 12;
constexpr int KKEEP = 1228;  // max(1, int(2048*0.6))

DEV f32x4 mfma16(bf16x8 a, bf16x8 b, f32x4 c) {
  return __builtin_amdgcn_mfma_f32_16x16x32_bf16(a, b, c, 0, 0, 0);
}
DEV float sigm(float x) { return 1.0f / (1.0f + __expf(-x)); }
DEV bf16x8 ld8(const __bf16* p) { return *reinterpret_cast<const bf16x8*>(p); }
DEV void st8(__bf16* p, bf16x8 v) { *reinterpret_cast<bf16x8*>(p) = v; }
// 16B-unit XOR swizzle within a 64-elem (128B) row: elem offset for (row, unit)
DEV int swzo(int row, int u) { return row * 64 + ((u ^ (row & 7)) << 3); }

// ---------------------------------------------------------------------------
// Transpose + cast: src f32 [K][N] -> dst bf16 [N][K]
// ---------------------------------------------------------------------------
__global__ void k_transpose_cast(const float* __restrict__ src,
                                 __bf16* __restrict__ dst, int K, int N) {
  __shared__ float tile[32][33];
  const int tx = threadIdx.x, ty = threadIdx.y;  // 32 x 8
  const int n0 = blockIdx.x * 32, k0 = blockIdx.y * 32;
  for (int i = 0; i < 4; ++i)
    tile[ty + 8 * i][tx] = src[(size_t)(k0 + ty + 8 * i) * N + n0 + tx];
  __syncthreads();
  for (int i = 0; i < 4; ++i)
    dst[(size_t)(n0 + ty + 8 * i) * K + k0 + tx] = (__bf16)tile[tx][ty + 8 * i];
}

// ---------------------------------------------------------------------------
// bf16 transpose: src [4096][768] -> dst [768][4096] (for V^T), 64x64 tiles.
// ---------------------------------------------------------------------------
__global__ void k_transpose_bf(const __bf16* __restrict__ src,
                               __bf16* __restrict__ dst) {
  __shared__ __bf16 t64[64][66];  // 66: 2-way max on transposed read
  const int tx = threadIdx.x, ty = threadIdx.y;  // 32 x 8
  const int c0 = blockIdx.x * 64, r0 = blockIdx.y * 64;
#pragma unroll
  for (int i = 0; i < 8; ++i) {
    union { u32 uu; __bf16 hh[2]; } cv;
    cv.uu = *reinterpret_cast<const u32*>(src + (size_t)(r0 + ty + 8 * i) * 768 +
                                          c0 + tx * 2);
    t64[ty + 8 * i][tx * 2] = cv.hh[0];
    t64[ty + 8 * i][tx * 2 + 1] = cv.hh[1];
  }
  __syncthreads();
#pragma unroll
  for (int i = 0; i < 8; ++i) {
    union { u32 uu; __bf16 hh[2]; } cv;
    cv.hh[0] = t64[tx * 2][ty + 8 * i];
    cv.hh[1] = t64[tx * 2 + 1][ty + 8 * i];
    *reinterpret_cast<u32*>(dst + (size_t)(c0 + ty + 8 * i) * 4096 + r0 + tx * 2) =
        cv.uu;
  }
}

// ---------------------------------------------------------------------------
// Router + RMSNorm1: one block per token.
// ---------------------------------------------------------------------------
__global__ __launch_bounds__(256) void k_router(
    const float* __restrict__ hid, const float* __restrict__ g1,
    const float* __restrict__ wmod, const float* __restrict__ bmod,
    const float* __restrict__ wtok, const float* __restrict__ btok,
    const int* __restrict__ temp, __bf16* __restrict__ normed,
    float* __restrict__ depth_out, float* __restrict__ actF,
    float* __restrict__ tokL) {
  const int t = blockIdx.x, tid = threadIdx.x;
  const float* x = hid + (size_t)t * DIM;
  float xs[3], gs[3], ss = 0.f, dm = 0.f, dt = 0.f;
  for (int j = 0; j < 3; ++j) {
    const int i = tid + 256 * j;
    const float xv = x[i], g = g1[i];
    xs[j] = xv; gs[j] = g;
    ss += xv * xv;
    dm += xv * wmod[i];
    dt += xv * g * wtok[i];
  }
  for (int m = 32; m >= 1; m >>= 1) {
    ss += __shfl_xor(ss, m);
    dm += __shfl_xor(dm, m);
    dt += __shfl_xor(dt, m);
  }
  __shared__ float red[4][3];
  if ((tid & 63) == 0) { red[tid >> 6][0] = ss; red[tid >> 6][1] = dm; red[tid >> 6][2] = dt; }
  __syncthreads();
  ss = red[0][0] + red[1][0] + red[2][0] + red[3][0];
  dm = red[0][1] + red[1][1] + red[2][1] + red[3][1];
  dt = red[0][2] + red[1][2] + red[2][2] + red[3][2];
  const float rms = rsqrtf(ss / 768.0f + 1e-6f);
  if (tid == 0) {
    const int iv = temp[0];
    const float T = (iv > -100000 && iv < 100000) ? (float)iv : __int_as_float(iv);
    const float z = (dm + bmod[0]) / T;
    depth_out[t] = sigm(z);
    actF[t] = z > 0.0f ? 1.0f : 0.0f;
    tokL[t] = rms * dt + btok[0];
  }
  for (int j = 0; j < 3; ++j) {
    const int i = tid + 256 * j;
    normed[(size_t)t * DIM + i] = (__bf16)(xs[j] * rms * gs[j]);
  }
}

// ---------------------------------------------------------------------------
// Top-k threshold: grid (2 halves, 2 batches) x 1024 thr.
// ---------------------------------------------------------------------------
__global__ __launch_bounds__(1024) void k_count(
    const float* __restrict__ tokL, float* __restrict__ kth_out) {
  const int b = blockIdx.y, tid = threadIdx.x;
  __shared__ float vals[2048];
  const float* L = tokL + (size_t)b * 2048;
  vals[tid] = L[tid];
  vals[tid + 1024] = L[tid + 1024];
  __syncthreads();
  const float e = vals[blockIdx.x * 1024 + tid];
  int gt = 0, ge = 0;
  const float4* v4 = reinterpret_cast<const float4*>(vals);
#pragma unroll 8
  for (int j = 0; j < 512; ++j) {
    const float4 q = v4[j];
    gt += (q.x > e) + (q.y > e) + (q.z > e) + (q.w > e);
    ge += (q.x >= e) + (q.y >= e) + (q.z >= e) + (q.w >= e);
  }
  if (gt < KKEEP && KKEEP <= ge) kth_out[b] = e;
}

__global__ __launch_bounds__(256) void k_mask(
    const float* __restrict__ tokL, const float* __restrict__ kth,
    const float* __restrict__ actF, float* __restrict__ mask_out,
    float* __restrict__ maskact) {
  const int i = blockIdx.x * 256 + threadIdx.x;  // 4096 tokens
  const int b = i >> 11;
  const float m = (tokL[i] >= kth[b]) ? 1.f : 0.f;
  mask_out[i] = m;
  maskact[i] = m * actF[i];
}

// ---------------------------------------------------------------------------
// RMSNorm2: h2 (f32) -> n2 (bf16) with gain g2
// ---------------------------------------------------------------------------
__global__ __launch_bounds__(256) void k_rmsnorm2(
    const float* __restrict__ h2, const float* __restrict__ g2,
    __bf16* __restrict__ n2) {
  const int t = blockIdx.x, tid = threadIdx.x;
  const float* x = h2 + (size_t)t * DIM;
  float xs[3], ss = 0.f;
  for (int j = 0; j < 3; ++j) { const float v = x[tid + 256 * j]; xs[j] = v; ss += v * v; }
  for (int m = 32; m >= 1; m >>= 1) ss += __shfl_xor(ss, m);
  __shared__ float red[4];
  if ((tid & 63) == 0) red[tid >> 6] = ss;
  __syncthreads();
  ss = red[0] + red[1] + red[2] + red[3];
  const float rms = rsqrtf(ss / 768.0f + 1e-6f);
  for (int j = 0; j < 3; ++j) {
    const int i = tid + 256 * j;
    n2[(size_t)t * DIM + i] = (__bf16)(xs[j] * rms * g2[i]);
  }
}

// ---------------------------------------------------------------------------
// GEMM: C[M][N] = A[M][K] * B[K][N], with B given TRANSPOSED (BT[N][K], bf16).
// 128x128 tile, 4 waves (2x2), 16x16x32 bf16 MFMA, BK=32, reg-prefetch.
// EPI: 0 plain->bf16   1 outF = epF + C*rowsc[row]  (f32)
//      2 gated = epB*sigm(C+bias[col]) -> bf16
//      3 t = silu(epB)*C -> bf16
// ---------------------------------------------------------------------------
template <int EPI>
__global__ __launch_bounds__(256) void k_gemm(
    const __bf16* __restrict__ A, const __bf16* __restrict__ BT,
    int N, int K, size_t bt_stride, size_t out_stride,
    __bf16* __restrict__ outB, float* __restrict__ outF,
    const float* __restrict__ epF, const __bf16* __restrict__ epB,
    const float* __restrict__ rowsc, const float* __restrict__ bias) {
  __shared__ __bf16 As[128][48];  // 48 pad: 96B rows keep 16B alignment
  __shared__ __bf16 Bs[128][48];
  const int tid = threadIdx.x;
  const int lane = tid & 63, w = tid >> 6;
  const int wr = w >> 1, wc = w & 1;
  const int f = lane & 15, e = lane >> 4;
  const int m0 = blockIdx.y * 128, n0 = blockIdx.x * 128;
  const __bf16* Bz = BT + (size_t)blockIdx.z * bt_stride;
  const int sr = tid >> 2, sc = (tid & 3) * 8;
  const __bf16* Ap = A + (size_t)(m0 + sr) * K + sc;
  const __bf16* Bp = Bz + (size_t)(n0 + sr) * K + sc;

  f32x4 acc[4][4] = {};
  bf16x8 ra0 = ld8(Ap), ra1 = ld8(Ap + (size_t)64 * K);
  bf16x8 rb0 = ld8(Bp), rb1 = ld8(Bp + (size_t)64 * K);
  int k0 = 0;
  while (true) {
    __syncthreads();
    st8(&As[sr][sc], ra0);  st8(&As[64 + sr][sc], ra1);
    st8(&Bs[sr][sc], rb0);  st8(&Bs[64 + sr][sc], rb1);
    __syncthreads();
    k0 += 32;
    if (k0 < K) {
      ra0 = ld8(Ap + k0);  ra1 = ld8(Ap + (size_t)64 * K + k0);
      rb0 = ld8(Bp + k0);  rb1 = ld8(Bp + (size_t)64 * K + k0);
    }
    bf16x8 af[4], bfr[4];
#pragma unroll
    for (int mi = 0; mi < 4; ++mi) af[mi] = ld8(&As[wr * 64 + mi * 16 + f][e * 8]);
#pragma unroll
    for (int ni = 0; ni < 4; ++ni) bfr[ni] = ld8(&Bs[wc * 64 + ni * 16 + f][e * 8]);
#pragma unroll
    for (int mi = 0; mi < 4; ++mi)
#pragma unroll
      for (int ni = 0; ni < 4; ++ni)
        acc[mi][ni] = mfma16(af[mi], bfr[ni], acc[mi][ni]);
    if (k0 >= K) break;
  }
  const size_t oz = (size_t)blockIdx.z * out_stride;
#pragma unroll
  for (int mi = 0; mi < 4; ++mi)
#pragma unroll
    for (int ni = 0; ni < 4; ++ni)
#pragma unroll
      for (int r = 0; r < 4; ++r) {
        const int row = m0 + wr * 64 + mi * 16 + e * 4 + r;
        const int col = n0 + wc * 64 + ni * 16 + f;
        const size_t idx = (size_t)row * N + col;
        const float c = acc[mi][ni][r];
        if constexpr (EPI == 0) {
          outB[oz + idx] = (__bf16)c;
        } else if constexpr (EPI == 1) {
          outF[idx] = epF[idx] + c * rowsc[row];
        } else if constexpr (EPI == 2) {
          outB[idx] = (__bf16)((float)epB[idx] * sigm(c + bias[col]));
        } else {
          const float u = (float)epB[idx];
          outB[idx] = (__bf16)(u * sigm(u) * c);
        }
      }
}

// ---------------------------------------------------------------------------
// Flash attention, causal.  QBLK=128 q-rows/block (4 waves x 32 rows, 2 frags),
// KVBLK=64 staged in XOR-swizzled LDS.  K from kbuf [tok][768]; V from vT
// [768][4096] (coalesced).  exp2-domain online softmax; only the last two KV
// tiles (t >= 2*qt) apply the causal mask.  Heavy q-tiles dispatched first.
// ---------------------------------------------------------------------------
__global__ __launch_bounds__(256) void k_attn(
    const __bf16* __restrict__ qb, const __bf16* __restrict__ kb,
    const __bf16* __restrict__ vT, __bf16* __restrict__ ctxb) {
  __shared__ __bf16 Ks[64 * 64];      // [key][d], swizzled 16B units
  __shared__ __bf16 Vt[64 * 64];      // [d][key], swizzled 16B units
  __shared__ __bf16 Pl[4][32][72];    // per-wave P tile [q][key]
  const int tid = threadIdx.x, lane = tid & 63, w = tid >> 6;
  const int f = lane & 15, e = lane >> 4;
  const int qt = (int)gridDim.x - 1 - (int)blockIdx.x;  // heavy first
  const int bh = blockIdx.y;
  const int b = bh / NH, h = bh % NH;
  const int q0 = qt * 128;
  const size_t base = (size_t)b * SEQ * DIM + (size_t)h * 64;
  const float SCALE2 = 0.125f * 1.4426950408889634f;  // /sqrt(64) * log2(e)

  bf16x8 aq[2][2];
#pragma unroll
  for (int fi = 0; fi < 2; ++fi) {
    const int qrow = q0 + w * 32 + fi * 16 + f;
    aq[fi][0] = ld8(qb + base + (size_t)qrow * DIM + e * 8);
    aq[fi][1] = ld8(qb + base + (size_t)qrow * DIM + 32 + e * 8);
  }
  float mrow[2][4], lrow[2][4];
  f32x4 cacc[2][4];
#pragma unroll
  for (int fi = 0; fi < 2; ++fi)
    for (int r = 0; r < 4; ++r) { mrow[fi][r] = -3.0e38f; lrow[fi][r] = 0.f; }
#pragma unroll
  for (int fi = 0; fi < 2; ++fi)
    for (int g = 0; g < 4; ++g) cacc[fi][g] = f32x4{0.f, 0.f, 0.f, 0.f};

  // staging: thread covers (row r1, 16B units u0 and u0+4)
  const int r1 = tid >> 2, u0 = tid & 3;
  const __bf16* kp = kb + base + (size_t)r1 * DIM;             // + t*64*DIM + u*8
  const __bf16* vp = vT + (size_t)(h * 64 + r1) * 4096 + b * 2048;  // + t*64 + u*8
  const int nt = 2 * qt + 2;

  bf16x8 rk0 = ld8(kp + u0 * 8), rk1 = ld8(kp + (u0 + 4) * 8);
  bf16x8 rv0 = ld8(vp + u0 * 8), rv1 = ld8(vp + (u0 + 4) * 8);

  for (int t = 0; t < nt; ++t) {
    __syncthreads();  // previous tile's LDS reads complete
    st8(&Ks[swzo(r1, u0)], rk0);  st8(&Ks[swzo(r1, u0 + 4)], rk1);
    st8(&Vt[swzo(r1, u0)], rv0);  st8(&Vt[swzo(r1, u0 + 4)], rv1);
    if (t + 1 < nt) {  // prefetch next tile while this one computes
      const size_t ko = (size_t)(t + 1) * 64 * DIM;
      rk0 = ld8(kp + ko + u0 * 8);  rk1 = ld8(kp + ko + (u0 + 4) * 8);
      const int vo = (t + 1) * 64;
      rv0 = ld8(vp + vo + u0 * 8);  rv1 = ld8(vp + vo + (u0 + 4) * 8);
    }
    __syncthreads();

    const bool need_mask = (t >= 2 * qt);
#pragma unroll
    for (int fi = 0; fi < 2; ++fi) {
      // S = QK^T (exp2 domain)
      f32x4 sacc[4];
#pragma unroll
      for (int g = 0; g < 4; ++g) {
        const int row = g * 16 + f;
        f32x4 z = f32x4{0.f, 0.f, 0.f, 0.f};
        z = mfma16(aq[fi][0], ld8(&Ks[swzo(row, e)]), z);
        z = mfma16(aq[fi][1], ld8(&Ks[swzo(row, e + 4)]), z);
        sacc[g] = z;
      }
      const int qg = q0 + w * 32 + fi * 16 + e * 4;
      float p[4][4], tm[4];
      for (int r = 0; r < 4; ++r) tm[r] = -3.0e38f;
#pragma unroll
      for (int g = 0; g < 4; ++g) {
        const int kg = t * 64 + g * 16 + f;
#pragma unroll
        for (int r = 0; r < 4; ++r) {
          float sv = sacc[g][r] * SCALE2;
          if (need_mask && (kg > qg + r)) sv = -1.0e30f;
          p[g][r] = sv;
          tm[r] = fmaxf(tm[r], sv);
        }
      }
      for (int m = 1; m < 16; m <<= 1)
        for (int r = 0; r < 4; ++r) tm[r] = fmaxf(tm[r], __shfl_xor(tm[r], m));
      float sc[4];
#pragma unroll
      for (int r = 0; r < 4; ++r) {
        const float mn = fmaxf(mrow[fi][r], tm[r]);
        sc[r] = exp2f(mrow[fi][r] - mn);
        mrow[fi][r] = mn;
      }
      float ps[4] = {0.f, 0.f, 0.f, 0.f};
#pragma unroll
      for (int g = 0; g < 4; ++g)
#pragma unroll
        for (int r = 0; r < 4; ++r) {
          const float pv = exp2f(p[g][r] - mrow[fi][r]);
          p[g][r] = pv;
          ps[r] += pv;
        }
      for (int m = 1; m < 16; m <<= 1)
        for (int r = 0; r < 4; ++r) ps[r] += __shfl_xor(ps[r], m);
#pragma unroll
      for (int r = 0; r < 4; ++r) lrow[fi][r] = lrow[fi][r] * sc[r] + ps[r];
#pragma unroll
      for (int g = 0; g < 4; ++g)
#pragma unroll
        for (int r = 0; r < 4; ++r) cacc[fi][g][r] *= sc[r];
#pragma unroll
      for (int g = 0; g < 4; ++g)
#pragma unroll
        for (int r = 0; r < 4; ++r)
          Pl[w][fi * 16 + e * 4 + r][g * 16 + f] = (__bf16)p[g][r];
    }
    // PV
#pragma unroll
    for (int fi = 0; fi < 2; ++fi) {
      const bf16x8 ap0 = ld8(&Pl[w][fi * 16 + f][e * 8]);
      const bf16x8 ap1 = ld8(&Pl[w][fi * 16 + f][32 + e * 8]);
#pragma unroll
      for (int g = 0; g < 4; ++g) {
        const int row = g * 16 + f;
        cacc[fi][g] = mfma16(ap0, ld8(&Vt[swzo(row, e)]), cacc[fi][g]);
        cacc[fi][g] = mfma16(ap1, ld8(&Vt[swzo(row, e + 4)]), cacc[fi][g]);
      }
    }
  }
#pragma unroll
  for (int fi = 0; fi < 2; ++fi) {
    float rcp[4];
    for (int r = 0; r < 4; ++r) rcp[r] = 1.0f / lrow[fi][r];
#pragma unroll
    for (int g = 0; g < 4; ++g)
#pragma unroll
      for (int r = 0; r < 4; ++r) {
        const int row = q0 + w * 32 + fi * 16 + e * 4 + r;
        ctxb[base + (size_t)row * DIM + g * 16 + f] = (__bf16)(cacc[fi][g][r] * rcp[r]);
      }
  }
}

// ---------------------------------------------------------------------------
extern "C" void kernel_launch(void* const* d_in, const int* in_sizes, int n_in,
                              void* d_out, int out_size, void* d_ws, size_t ws_size,
                              hipStream_t stream) {
  const float* hid   = (const float*)d_in[0];
  const int*   temp  = (const int*)d_in[2];
  const float* wq    = (const float*)d_in[3];
  const float* wk    = (const float*)d_in[4];
  const float* wv    = (const float*)d_in[5];
  const float* wo    = (const float*)d_in[6];
  const float* w1    = (const float*)d_in[7];
  const float* w3    = (const float*)d_in[8];
  const float* w2    = (const float*)d_in[9];
  const float* g1    = (const float*)d_in[10];
  const float* g2    = (const float*)d_in[11];
  const float* wmod  = (const float*)d_in[12];
  const float* bmod  = (const float*)d_in[13];
  const float* wtok  = (const float*)d_in[14];
  const float* btok  = (const float*)d_in[15];
  const float* wgate = (const float*)d_in[16];
  const float* bgate = (const float*)d_in[17];

  char* ws = (char*)d_ws;
  __bf16* WT = (__bf16*)ws;                       // 7,667,712 elems bf16
  const size_t oWQ = 0, oWK = 589824, oWV = 1179648, oWO = 1769472,
               oWG = 2359296, oW1 = 2949120, oW3 = 4521984, oW2 = 6094848;
  __bf16* qbuf   = (__bf16*)(ws + 15335424);      // arenaQ: q|k|v (later U)
  __bf16* kbuf   = qbuf + 3145728;
  __bf16* vbuf   = kbuf + 3145728;
  __bf16* Ubuf   = qbuf;                          // alias (qkv dead after attn)
  __bf16* normed = (__bf16*)(ws + 34209792);      // arenaN: normed|ctx|n2
  __bf16* ctxb   = normed + 3145728;
  __bf16* n2buf  = ctxb + 3145728;
  __bf16* vTbuf  = normed;                        // alias (normed dead after QKV)
  __bf16* tbuf   = normed;                        // alias (vT dead after attn)
  float*  h2     = (float*)(ws + 53084160);
  __bf16* gated  = (__bf16*)(ws + 65667072);
  float*  tokL   = (float*)(ws + 71958528);
  float*  actF   = tokL + 4096;
  float*  maskact = actF + 4096;
  float*  kthbuf  = maskact + 4096;

  float* dout = (float*)d_out;
  float* out_hidden = dout;
  float* out_depth  = dout + 3145728;
  float* out_mask   = dout + 3145728 + 4096;

  const dim3 tb(32, 8);
  k_transpose_cast<<<dim3(24, 24), tb, 0, stream>>>(wq,    WT + oWQ, 768, 768);
  k_transpose_cast<<<dim3(24, 24), tb, 0, stream>>>(wk,    WT + oWK, 768, 768);
  k_transpose_cast<<<dim3(24, 24), tb, 0, stream>>>(wv,    WT + oWV, 768, 768);
  k_transpose_cast<<<dim3(24, 24), tb, 0, stream>>>(wo,    WT + oWO, 768, 768);
  k_transpose_cast<<<dim3(24, 24), tb, 0, stream>>>(wgate, WT + oWG, 768, 768);
  k_transpose_cast<<<dim3(64, 24), tb, 0, stream>>>(w1,    WT + oW1, 768, 2048);
  k_transpose_cast<<<dim3(64, 24), tb, 0, stream>>>(w3,    WT + oW3, 768, 2048);
  k_transpose_cast<<<dim3(24, 64), tb, 0, stream>>>(w2,    WT + oW2, 2048, 768);

  k_router<<<4096, 256, 0, stream>>>(hid, g1, wmod, bmod, wtok, btok, temp,
                                     normed, out_depth, actF, tokL);
  k_count<<<dim3(2, 2), 1024, 0, stream>>>(tokL, kthbuf);
  k_mask<<<16, 256, 0, stream>>>(tokL, kthbuf, actF, out_mask, maskact);

  // q,k,v = normed @ {wq,wk,wv}
  k_gemm<0><<<dim3(6, 32, 3), 256, 0, stream>>>(
      normed, WT + oWQ, 768, 768, 589824, 3145728,
      qbuf, nullptr, nullptr, nullptr, nullptr, nullptr);

  // vT[768][4096] = vbuf^T   (overwrites normed, which is now dead)
  k_transpose_bf<<<dim3(12, 64), tb, 0, stream>>>(vbuf, vTbuf);

  k_attn<<<dim3(16, 24), 256, 0, stream>>>(qbuf, kbuf, vTbuf, ctxb);

  // h2 = hidden + (ctx @ wo) * mask * active   (f32)
  k_gemm<1><<<dim3(6, 32, 1), 256, 0, stream>>>(
      ctxb, WT + oWO, 768, 768, 0, 0,
      nullptr, h2, hid, nullptr, maskact, nullptr);

  k_rmsnorm2<<<4096, 256, 0, stream>>>(h2, g2, n2buf);

  // gated = n2 * sigmoid(n2 @ wgate + bgate)
  k_gemm<2><<<dim3(6, 32, 1), 256, 0, stream>>>(
      n2buf, WT + oWG, 768, 768, 0, 0,
      gated, nullptr, nullptr, n2buf, nullptr, bgate);

  // U = gated @ w1
  k_gemm<0><<<dim3(16, 32, 1), 256, 0, stream>>>(
      gated, WT + oW1, 2048, 768, 0, 0,
      Ubuf, nullptr, nullptr, nullptr, nullptr, nullptr);

  // t = silu(U) * (gated @ w3)
  k_gemm<3><<<dim3(16, 32, 1), 256, 0, stream>>>(
      gated, WT + oW3, 2048, 768, 0, 0,
      tbuf, nullptr, nullptr, Ubuf, nullptr, nullptr);

  // out_hidden = h2 + (t @ w2) * active   (f32, straight to d_out)
  k_gemm<1><<<dim3(6, 32, 1), 256, 0, stream>>>(
      tbuf, WT + oW2, 768, 2048, 0, 0,
      nullptr, out_hidden, h2, nullptr, actF, nullptr);

  (void)in_sizes; (void)n_in; (void)out_size; (void)ws_size;
}

// Round 5
// 308.279 us; speedup vs baseline: 1.2109x; 1.2109x over previous
//
#include <hip/hip_runtime.h>

// ============================================================================
// MoR block: depth router + token top-k + RMSNorm + causal MHA + ACM gate +
// SwiGLU MLP.  B=2 S=2048 D=768 H=12 Dh=64 F=2048.
// Outputs (f32, concat): hidden[2,2048,768] | depth_probs[2,2048] | mask[2,2048]
// Round 5: split-KV flash attention (flash-decoding).  QBLK=64 (4 waves x 16
// q-rows), KV split into 512-key chunks -> 1920 blocks (was 384), max 8 tiles
// critical path (was 32).  Partial (O,m,l) in ws (aliases dead h2/gated),
// combined by k_attn_combine.  Round-4 attn was parallelism-bound: occupancy
// 7.6%, MfmaUtil 3.9% at 136us.
// ============================================================================

typedef float f32x4 __attribute__((ext_vector_type(4)));
typedef __bf16 bf16x8 __attribute__((ext_vector_type(8)));
typedef unsigned int u32;

#define DEV static __device__ __forceinline__

constexpr int SEQ = 2048, DIM = 768, NH = 12;
constexpr int KKEEP = 1228;  // max(1, int(2048*0.6))

DEV f32x4 mfma16(bf16x8 a, bf16x8 b, f32x4 c) {
  return __builtin_amdgcn_mfma_f32_16x16x32_bf16(a, b, c, 0, 0, 0);
}
DEV float sigm(float x) { return 1.0f / (1.0f + __expf(-x)); }
DEV bf16x8 ld8(const __bf16* p) { return *reinterpret_cast<const bf16x8*>(p); }
DEV void st8(__bf16* p, bf16x8 v) { *reinterpret_cast<bf16x8*>(p) = v; }
// 16B-unit XOR swizzle within a 64-elem (128B) row: elem offset for (row, unit)
DEV int swzo(int row, int u) { return row * 64 + ((u ^ (row & 7)) << 3); }

// ---------------------------------------------------------------------------
// Transpose + cast: src f32 [K][N] -> dst bf16 [N][K]
// ---------------------------------------------------------------------------
__global__ void k_transpose_cast(const float* __restrict__ src,
                                 __bf16* __restrict__ dst, int K, int N) {
  __shared__ float tile[32][33];
  const int tx = threadIdx.x, ty = threadIdx.y;  // 32 x 8
  const int n0 = blockIdx.x * 32, k0 = blockIdx.y * 32;
  for (int i = 0; i < 4; ++i)
    tile[ty + 8 * i][tx] = src[(size_t)(k0 + ty + 8 * i) * N + n0 + tx];
  __syncthreads();
  for (int i = 0; i < 4; ++i)
    dst[(size_t)(n0 + ty + 8 * i) * K + k0 + tx] = (__bf16)tile[tx][ty + 8 * i];
}

// ---------------------------------------------------------------------------
// bf16 transpose: src [4096][768] -> dst [768][4096] (for V^T), 64x64 tiles.
// ---------------------------------------------------------------------------
__global__ void k_transpose_bf(const __bf16* __restrict__ src,
                               __bf16* __restrict__ dst) {
  __shared__ __bf16 t64[64][66];
  const int tx = threadIdx.x, ty = threadIdx.y;  // 32 x 8
  const int c0 = blockIdx.x * 64, r0 = blockIdx.y * 64;
#pragma unroll
  for (int i = 0; i < 8; ++i) {
    union { u32 uu; __bf16 hh[2]; } cv;
    cv.uu = *reinterpret_cast<const u32*>(src + (size_t)(r0 + ty + 8 * i) * 768 +
                                          c0 + tx * 2);
    t64[ty + 8 * i][tx * 2] = cv.hh[0];
    t64[ty + 8 * i][tx * 2 + 1] = cv.hh[1];
  }
  __syncthreads();
#pragma unroll
  for (int i = 0; i < 8; ++i) {
    union { u32 uu; __bf16 hh[2]; } cv;
    cv.hh[0] = t64[tx * 2][ty + 8 * i];
    cv.hh[1] = t64[tx * 2 + 1][ty + 8 * i];
    *reinterpret_cast<u32*>(dst + (size_t)(c0 + ty + 8 * i) * 4096 + r0 + tx * 2) =
        cv.uu;
  }
}

// ---------------------------------------------------------------------------
// Router + RMSNorm1: one block per token.
// ---------------------------------------------------------------------------
__global__ __launch_bounds__(256) void k_router(
    const float* __restrict__ hid, const float* __restrict__ g1,
    const float* __restrict__ wmod, const float* __restrict__ bmod,
    const float* __restrict__ wtok, const float* __restrict__ btok,
    const int* __restrict__ temp, __bf16* __restrict__ normed,
    float* __restrict__ depth_out, float* __restrict__ actF,
    float* __restrict__ tokL) {
  const int t = blockIdx.x, tid = threadIdx.x;
  const float* x = hid + (size_t)t * DIM;
  float xs[3], gs[3], ss = 0.f, dm = 0.f, dt = 0.f;
  for (int j = 0; j < 3; ++j) {
    const int i = tid + 256 * j;
    const float xv = x[i], g = g1[i];
    xs[j] = xv; gs[j] = g;
    ss += xv * xv;
    dm += xv * wmod[i];
    dt += xv * g * wtok[i];
  }
  for (int m = 32; m >= 1; m >>= 1) {
    ss += __shfl_xor(ss, m);
    dm += __shfl_xor(dm, m);
    dt += __shfl_xor(dt, m);
  }
  __shared__ float red[4][3];
  if ((tid & 63) == 0) { red[tid >> 6][0] = ss; red[tid >> 6][1] = dm; red[tid >> 6][2] = dt; }
  __syncthreads();
  ss = red[0][0] + red[1][0] + red[2][0] + red[3][0];
  dm = red[0][1] + red[1][1] + red[2][1] + red[3][1];
  dt = red[0][2] + red[1][2] + red[2][2] + red[3][2];
  const float rms = rsqrtf(ss / 768.0f + 1e-6f);
  if (tid == 0) {
    const int iv = temp[0];
    const float T = (iv > -100000 && iv < 100000) ? (float)iv : __int_as_float(iv);
    const float z = (dm + bmod[0]) / T;
    depth_out[t] = sigm(z);
    actF[t] = z > 0.0f ? 1.0f : 0.0f;
    tokL[t] = rms * dt + btok[0];
  }
  for (int j = 0; j < 3; ++j) {
    const int i = tid + 256 * j;
    normed[(size_t)t * DIM + i] = (__bf16)(xs[j] * rms * gs[j]);
  }
}

// ---------------------------------------------------------------------------
// Top-k threshold: grid (2 halves, 2 batches) x 1024 thr.
// ---------------------------------------------------------------------------
__global__ __launch_bounds__(1024) void k_count(
    const float* __restrict__ tokL, float* __restrict__ kth_out) {
  const int b = blockIdx.y, tid = threadIdx.x;
  __shared__ float vals[2048];
  const float* L = tokL + (size_t)b * 2048;
  vals[tid] = L[tid];
  vals[tid + 1024] = L[tid + 1024];
  __syncthreads();
  const float e = vals[blockIdx.x * 1024 + tid];
  int gt = 0, ge = 0;
  const float4* v4 = reinterpret_cast<const float4*>(vals);
#pragma unroll 8
  for (int j = 0; j < 512; ++j) {
    const float4 q = v4[j];
    gt += (q.x > e) + (q.y > e) + (q.z > e) + (q.w > e);
    ge += (q.x >= e) + (q.y >= e) + (q.z >= e) + (q.w >= e);
  }
  if (gt < KKEEP && KKEEP <= ge) kth_out[b] = e;
}

__global__ __launch_bounds__(256) void k_mask(
    const float* __restrict__ tokL, const float* __restrict__ kth,
    const float* __restrict__ actF, float* __restrict__ mask_out,
    float* __restrict__ maskact) {
  const int i = blockIdx.x * 256 + threadIdx.x;  // 4096 tokens
  const int b = i >> 11;
  const float m = (tokL[i] >= kth[b]) ? 1.f : 0.f;
  mask_out[i] = m;
  maskact[i] = m * actF[i];
}

// ---------------------------------------------------------------------------
// RMSNorm2: h2 (f32) -> n2 (bf16) with gain g2
// ---------------------------------------------------------------------------
__global__ __launch_bounds__(256) void k_rmsnorm2(
    const float* __restrict__ h2, const float* __restrict__ g2,
    __bf16* __restrict__ n2) {
  const int t = blockIdx.x, tid = threadIdx.x;
  const float* x = h2 + (size_t)t * DIM;
  float xs[3], ss = 0.f;
  for (int j = 0; j < 3; ++j) { const float v = x[tid + 256 * j]; xs[j] = v; ss += v * v; }
  for (int m = 32; m >= 1; m >>= 1) ss += __shfl_xor(ss, m);
  __shared__ float red[4];
  if ((tid & 63) == 0) red[tid >> 6] = ss;
  __syncthreads();
  ss = red[0] + red[1] + red[2] + red[3];
  const float rms = rsqrtf(ss / 768.0f + 1e-6f);
  for (int j = 0; j < 3; ++j) {
    const int i = tid + 256 * j;
    n2[(size_t)t * DIM + i] = (__bf16)(xs[j] * rms * g2[i]);
  }
}

// ---------------------------------------------------------------------------
// GEMM: C[M][N] = A[M][K] * B[K][N], with B given TRANSPOSED (BT[N][K], bf16).
// 128x128 tile, 4 waves (2x2), 16x16x32 bf16 MFMA, BK=32, reg-prefetch.
// EPI: 0 plain->bf16   1 outF = epF + C*rowsc[row]  (f32)
//      2 gated = epB*sigm(C+bias[col]) -> bf16
//      3 t = silu(epB)*C -> bf16
// ---------------------------------------------------------------------------
template <int EPI>
__global__ __launch_bounds__(256) void k_gemm(
    const __bf16* __restrict__ A, const __bf16* __restrict__ BT,
    int N, int K, size_t bt_stride, size_t out_stride,
    __bf16* __restrict__ outB, float* __restrict__ outF,
    const float* __restrict__ epF, const __bf16* __restrict__ epB,
    const float* __restrict__ rowsc, const float* __restrict__ bias) {
  __shared__ __bf16 As[128][48];  // 48 pad: 96B rows keep 16B alignment
  __shared__ __bf16 Bs[128][48];
  const int tid = threadIdx.x;
  const int lane = tid & 63, w = tid >> 6;
  const int wr = w >> 1, wc = w & 1;
  const int f = lane & 15, e = lane >> 4;
  const int m0 = blockIdx.y * 128, n0 = blockIdx.x * 128;
  const __bf16* Bz = BT + (size_t)blockIdx.z * bt_stride;
  const int sr = tid >> 2, sc = (tid & 3) * 8;
  const __bf16* Ap = A + (size_t)(m0 + sr) * K + sc;
  const __bf16* Bp = Bz + (size_t)(n0 + sr) * K + sc;

  f32x4 acc[4][4] = {};
  bf16x8 ra0 = ld8(Ap), ra1 = ld8(Ap + (size_t)64 * K);
  bf16x8 rb0 = ld8(Bp), rb1 = ld8(Bp + (size_t)64 * K);
  int k0 = 0;
  while (true) {
    __syncthreads();
    st8(&As[sr][sc], ra0);  st8(&As[64 + sr][sc], ra1);
    st8(&Bs[sr][sc], rb0);  st8(&Bs[64 + sr][sc], rb1);
    __syncthreads();
    k0 += 32;
    if (k0 < K) {
      ra0 = ld8(Ap + k0);  ra1 = ld8(Ap + (size_t)64 * K + k0);
      rb0 = ld8(Bp + k0);  rb1 = ld8(Bp + (size_t)64 * K + k0);
    }
    bf16x8 af[4], bfr[4];
#pragma unroll
    for (int mi = 0; mi < 4; ++mi) af[mi] = ld8(&As[wr * 64 + mi * 16 + f][e * 8]);
#pragma unroll
    for (int ni = 0; ni < 4; ++ni) bfr[ni] = ld8(&Bs[wc * 64 + ni * 16 + f][e * 8]);
#pragma unroll
    for (int mi = 0; mi < 4; ++mi)
#pragma unroll
      for (int ni = 0; ni < 4; ++ni)
        acc[mi][ni] = mfma16(af[mi], bfr[ni], acc[mi][ni]);
    if (k0 >= K) break;
  }
  const size_t oz = (size_t)blockIdx.z * out_stride;
#pragma unroll
  for (int mi = 0; mi < 4; ++mi)
#pragma unroll
    for (int ni = 0; ni < 4; ++ni)
#pragma unroll
      for (int r = 0; r < 4; ++r) {
        const int row = m0 + wr * 64 + mi * 16 + e * 4 + r;
        const int col = n0 + wc * 64 + ni * 16 + f;
        const size_t idx = (size_t)row * N + col;
        const float c = acc[mi][ni][r];
        if constexpr (EPI == 0) {
          outB[oz + idx] = (__bf16)c;
        } else if constexpr (EPI == 1) {
          outF[idx] = epF[idx] + c * rowsc[row];
        } else if constexpr (EPI == 2) {
          outB[idx] = (__bf16)((float)epB[idx] * sigm(c + bias[col]));
        } else {
          const float u = (float)epB[idx];
          outB[idx] = (__bf16)(u * sigm(u) * c);
        }
      }
}

// ---------------------------------------------------------------------------
// Split-KV flash attention, causal.  Each block: one 64-row q-tile x one
// 512-key KV chunk (<= 8 tiles of 64).  Grid x enumerates the 80 (qt,c) slots
// per bh (qt 0..31, nchunk(qt) = qt/8+1), y = bh.  Writes unnormalized
// partial O (bf16) + (m,l) f32, exp2-domain.  4 waves x 16 q-rows.
// ---------------------------------------------------------------------------
__global__ __launch_bounds__(256) void k_attn(
    const __bf16* __restrict__ qb, const __bf16* __restrict__ kb,
    const __bf16* __restrict__ vT, __bf16* __restrict__ Opart,
    float* __restrict__ ml) {
  __shared__ __bf16 Ks[64 * 64];      // [key][d], swizzled 16B units
  __shared__ __bf16 Vt[64 * 64];      // [d][key], swizzled 16B units
  __shared__ __bf16 Pl[4][16][72];    // per-wave P tile [q][key]
  const int tid = threadIdx.x, lane = tid & 63, w = tid >> 6;
  const int f = lane & 15, e = lane >> 4;
  const int idx = 79 - (int)blockIdx.x;  // heavy chunks first
  int g4, rel;
  if (idx < 8)       { g4 = 0; rel = idx; }
  else if (idx < 24) { g4 = 1; rel = idx - 8; }
  else if (idx < 48) { g4 = 2; rel = idx - 24; }
  else               { g4 = 3; rel = idx - 48; }
  const int qt = (g4 << 3) + rel / (g4 + 1);
  const int c  = rel % (g4 + 1);
  const int bh = blockIdx.y;
  const int b = bh / NH, h = bh % NH;
  const int slot = bh * 80 + idx;
  const int q0 = qt * 64;
  const int kt0 = c * 8;
  const int ntile = min(8, qt + 1 - kt0);
  const size_t base = (size_t)b * SEQ * DIM + (size_t)h * 64;
  const float SCALE2 = 0.125f * 1.4426950408889634f;  // /sqrt(64) * log2(e)

  const int qrow = q0 + w * 16 + f;
  const bf16x8 aq0 = ld8(qb + base + (size_t)qrow * DIM + e * 8);
  const bf16x8 aq1 = ld8(qb + base + (size_t)qrow * DIM + 32 + e * 8);
  float mrow[4], lrow[4];
  f32x4 cacc[4];
  for (int r = 0; r < 4; ++r) { mrow[r] = -3.0e38f; lrow[r] = 0.f; }
  for (int g = 0; g < 4; ++g) cacc[g] = f32x4{0.f, 0.f, 0.f, 0.f};

  // staging: thread covers (row r1, 16B units u0 and u0+4)
  const int r1 = tid >> 2, u0 = tid & 3;
  const __bf16* kp = kb + base + (size_t)r1 * DIM;
  const __bf16* vp = vT + (size_t)(h * 64 + r1) * 4096 + b * 2048;

  bf16x8 rk0 = ld8(kp + (size_t)(kt0 * 64) * DIM + u0 * 8);
  bf16x8 rk1 = ld8(kp + (size_t)(kt0 * 64) * DIM + (u0 + 4) * 8);
  bf16x8 rv0 = ld8(vp + kt0 * 64 + u0 * 8);
  bf16x8 rv1 = ld8(vp + kt0 * 64 + (u0 + 4) * 8);

  for (int tt = 0; tt < ntile; ++tt) {
    const int kt = kt0 + tt;
    __syncthreads();
    st8(&Ks[swzo(r1, u0)], rk0);  st8(&Ks[swzo(r1, u0 + 4)], rk1);
    st8(&Vt[swzo(r1, u0)], rv0);  st8(&Vt[swzo(r1, u0 + 4)], rv1);
    if (tt + 1 < ntile) {
      const size_t ko = (size_t)((kt + 1) * 64) * DIM;
      rk0 = ld8(kp + ko + u0 * 8);  rk1 = ld8(kp + ko + (u0 + 4) * 8);
      const int vo = (kt + 1) * 64;
      rv0 = ld8(vp + vo + u0 * 8);  rv1 = ld8(vp + vo + (u0 + 4) * 8);
    }
    __syncthreads();

    // S = QK^T (exp2 domain)
    f32x4 sacc[4];
#pragma unroll
    for (int g = 0; g < 4; ++g) {
      const int row = g * 16 + f;
      f32x4 z = f32x4{0.f, 0.f, 0.f, 0.f};
      z = mfma16(aq0, ld8(&Ks[swzo(row, e)]), z);
      z = mfma16(aq1, ld8(&Ks[swzo(row, e + 4)]), z);
      sacc[g] = z;
    }
    const bool need_mask = (kt == qt);
    const int qg = q0 + w * 16 + e * 4;
    float p[4][4], tm[4];
    for (int r = 0; r < 4; ++r) tm[r] = -3.0e38f;
#pragma unroll
    for (int g = 0; g < 4; ++g) {
      const int kg = kt * 64 + g * 16 + f;
#pragma unroll
      for (int r = 0; r < 4; ++r) {
        float sv = sacc[g][r] * SCALE2;
        if (need_mask && (kg > qg + r)) sv = -1.0e30f;
        p[g][r] = sv;
        tm[r] = fmaxf(tm[r], sv);
      }
    }
    for (int m = 1; m < 16; m <<= 1)
      for (int r = 0; r < 4; ++r) tm[r] = fmaxf(tm[r], __shfl_xor(tm[r], m));
    float sc[4];
#pragma unroll
    for (int r = 0; r < 4; ++r) {
      const float mn = fmaxf(mrow[r], tm[r]);
      sc[r] = exp2f(mrow[r] - mn);
      mrow[r] = mn;
    }
    float ps[4] = {0.f, 0.f, 0.f, 0.f};
#pragma unroll
    for (int g = 0; g < 4; ++g)
#pragma unroll
      for (int r = 0; r < 4; ++r) {
        const float pv = exp2f(p[g][r] - mrow[r]);
        p[g][r] = pv;
        ps[r] += pv;
      }
    for (int m = 1; m < 16; m <<= 1)
      for (int r = 0; r < 4; ++r) ps[r] += __shfl_xor(ps[r], m);
#pragma unroll
    for (int r = 0; r < 4; ++r) lrow[r] = lrow[r] * sc[r] + ps[r];
#pragma unroll
    for (int g = 0; g < 4; ++g)
#pragma unroll
      for (int r = 0; r < 4; ++r) cacc[g][r] *= sc[r];
#pragma unroll
    for (int g = 0; g < 4; ++g)
#pragma unroll
      for (int r = 0; r < 4; ++r) Pl[w][e * 4 + r][g * 16 + f] = (__bf16)p[g][r];
    const bf16x8 ap0 = ld8(&Pl[w][f][e * 8]);
    const bf16x8 ap1 = ld8(&Pl[w][f][32 + e * 8]);
#pragma unroll
    for (int g = 0; g < 4; ++g) {
      const int row = g * 16 + f;
      cacc[g] = mfma16(ap0, ld8(&Vt[swzo(row, e)]), cacc[g]);
      cacc[g] = mfma16(ap1, ld8(&Vt[swzo(row, e + 4)]), cacc[g]);
    }
  }
  // write partials (unnormalized O, exp2-domain m, l)
  if (f == 0) {
#pragma unroll
    for (int r = 0; r < 4; ++r) {
      const int row = w * 16 + e * 4 + r;
      ml[(size_t)slot * 128 + row * 2] = mrow[r];
      ml[(size_t)slot * 128 + row * 2 + 1] = lrow[r];
    }
  }
#pragma unroll
  for (int g = 0; g < 4; ++g)
#pragma unroll
    for (int r = 0; r < 4; ++r) {
      const int row = w * 16 + e * 4 + r;
      Opart[(size_t)slot * 4096 + row * 64 + g * 16 + f] = (__bf16)cacc[g][r];
    }
}

// ---------------------------------------------------------------------------
// Combine partials: grid (32 qt, 24 bh) x 256.  Thread = (row = tid/4,
// 16 dims at (tid%4)*16).  nchunk = qt/8+1 <= 4.
// ---------------------------------------------------------------------------
__global__ __launch_bounds__(256) void k_attn_combine(
    const __bf16* __restrict__ Opart, const float* __restrict__ ml,
    __bf16* __restrict__ ctxb) {
  const int qt = blockIdx.x, bh = blockIdx.y;
  const int b = bh / NH, h = bh % NH;
  const int g = qt >> 3;
  const int sb = bh * 80 + 4 * g * (g + 1) + (qt & 7) * (g + 1);
  const int nch = g + 1;
  const int row = threadIdx.x >> 2, dh0 = (threadIdx.x & 3) * 16;

  float m = -3.0e38f;
  for (int cc = 0; cc < nch; ++cc)
    m = fmaxf(m, ml[(size_t)(sb + cc) * 128 + row * 2]);
  float ltot = 0.f;
  float acc[16];
#pragma unroll
  for (int j = 0; j < 16; ++j) acc[j] = 0.f;
  for (int cc = 0; cc < nch; ++cc) {
    const float mc = ml[(size_t)(sb + cc) * 128 + row * 2];
    const float lc = ml[(size_t)(sb + cc) * 128 + row * 2 + 1];
    const float wc = exp2f(mc - m);
    ltot += wc * lc;
    const __bf16* op = Opart + (size_t)(sb + cc) * 4096 + row * 64 + dh0;
    const bf16x8 o0 = ld8(op), o1 = ld8(op + 8);
#pragma unroll
    for (int j = 0; j < 8; ++j) {
      acc[j] += wc * (float)o0[j];
      acc[8 + j] += wc * (float)o1[j];
    }
  }
  const float rl = 1.0f / ltot;
  bf16x8 w0, w1;
#pragma unroll
  for (int j = 0; j < 8; ++j) {
    w0[j] = (__bf16)(acc[j] * rl);
    w1[j] = (__bf16)(acc[8 + j] * rl);
  }
  const size_t base = (size_t)b * SEQ * DIM + (size_t)h * 64;
  __bf16* dst = ctxb + base + (size_t)(qt * 64 + row) * DIM + dh0;
  st8(dst, w0);
  st8(dst + 8, w1);
}

// ---------------------------------------------------------------------------
extern "C" void kernel_launch(void* const* d_in, const int* in_sizes, int n_in,
                              void* d_out, int out_size, void* d_ws, size_t ws_size,
                              hipStream_t stream) {
  const float* hid   = (const float*)d_in[0];
  const int*   temp  = (const int*)d_in[2];
  const float* wq    = (const float*)d_in[3];
  const float* wk    = (const float*)d_in[4];
  const float* wv    = (const float*)d_in[5];
  const float* wo    = (const float*)d_in[6];
  const float* w1    = (const float*)d_in[7];
  const float* w3    = (const float*)d_in[8];
  const float* w2    = (const float*)d_in[9];
  const float* g1    = (const float*)d_in[10];
  const float* g2    = (const float*)d_in[11];
  const float* wmod  = (const float*)d_in[12];
  const float* bmod  = (const float*)d_in[13];
  const float* wtok  = (const float*)d_in[14];
  const float* btok  = (const float*)d_in[15];
  const float* wgate = (const float*)d_in[16];
  const float* bgate = (const float*)d_in[17];

  char* ws = (char*)d_ws;
  __bf16* WT = (__bf16*)ws;                       // 7,667,712 elems bf16
  const size_t oWQ = 0, oWK = 589824, oWV = 1179648, oWO = 1769472,
               oWG = 2359296, oW1 = 2949120, oW3 = 4521984, oW2 = 6094848;
  __bf16* qbuf   = (__bf16*)(ws + 15335424);      // arenaQ: q|k|v (later U)
  __bf16* kbuf   = qbuf + 3145728;
  __bf16* vbuf   = kbuf + 3145728;
  __bf16* Ubuf   = qbuf;                          // alias (qkv dead after attn)
  __bf16* normed = (__bf16*)(ws + 34209792);      // arenaN: normed|ctx|n2
  __bf16* ctxb   = normed + 3145728;
  __bf16* n2buf  = ctxb + 3145728;
  __bf16* vTbuf  = normed;                        // alias (normed dead after QKV)
  __bf16* tbuf   = normed;                        // alias (vT dead after attn)
  float*  h2     = (float*)(ws + 53084160);
  __bf16* gated  = (__bf16*)(ws + 65667072);
  // attention partials alias the (currently dead) h2+gated arenas:
  __bf16* Opart  = (__bf16*)(ws + 53084160);      // 1920*4096*2B = 15.7MB
  float*  mlbuf  = (float*)(ws + 68812800);       // 1920*128*4B  = 983KB
  float*  tokL   = (float*)(ws + 71958528);
  float*  actF   = tokL + 4096;
  float*  maskact = actF + 4096;
  float*  kthbuf  = maskact + 4096;

  float* dout = (float*)d_out;
  float* out_hidden = dout;
  float* out_depth  = dout + 3145728;
  float* out_mask   = dout + 3145728 + 4096;

  const dim3 tb(32, 8);
  k_transpose_cast<<<dim3(24, 24), tb, 0, stream>>>(wq,    WT + oWQ, 768, 768);
  k_transpose_cast<<<dim3(24, 24), tb, 0, stream>>>(wk,    WT + oWK, 768, 768);
  k_transpose_cast<<<dim3(24, 24), tb, 0, stream>>>(wv,    WT + oWV, 768, 768);
  k_transpose_cast<<<dim3(24, 24), tb, 0, stream>>>(wo,    WT + oWO, 768, 768);
  k_transpose_cast<<<dim3(24, 24), tb, 0, stream>>>(wgate, WT + oWG, 768, 768);
  k_transpose_cast<<<dim3(64, 24), tb, 0, stream>>>(w1,    WT + oW1, 768, 2048);
  k_transpose_cast<<<dim3(64, 24), tb, 0, stream>>>(w3,    WT + oW3, 768, 2048);
  k_transpose_cast<<<dim3(24, 64), tb, 0, stream>>>(w2,    WT + oW2, 2048, 768);

  k_router<<<4096, 256, 0, stream>>>(hid, g1, wmod, bmod, wtok, btok, temp,
                                     normed, out_depth, actF, tokL);
  k_count<<<dim3(2, 2), 1024, 0, stream>>>(tokL, kthbuf);
  k_mask<<<16, 256, 0, stream>>>(tokL, kthbuf, actF, out_mask, maskact);

  // q,k,v = normed @ {wq,wk,wv}
  k_gemm<0><<<dim3(6, 32, 3), 256, 0, stream>>>(
      normed, WT + oWQ, 768, 768, 589824, 3145728,
      qbuf, nullptr, nullptr, nullptr, nullptr, nullptr);

  // vT[768][4096] = vbuf^T   (overwrites normed, which is now dead)
  k_transpose_bf<<<dim3(12, 64), tb, 0, stream>>>(vbuf, vTbuf);

  // split-KV attention: 80 (qt,chunk) slots x 24 bh
  k_attn<<<dim3(80, 24), 256, 0, stream>>>(qbuf, kbuf, vTbuf, Opart, mlbuf);
  k_attn_combine<<<dim3(32, 24), 256, 0, stream>>>(Opart, mlbuf, ctxb);

  // h2 = hidden + (ctx @ wo) * mask * active   (f32)
  k_gemm<1><<<dim3(6, 32, 1), 256, 0, stream>>>(
      ctxb, WT + oWO, 768, 768, 0, 0,
      nullptr, h2, hid, nullptr, maskact, nullptr);

  k_rmsnorm2<<<4096, 256, 0, stream>>>(h2, g2, n2buf);

  // gated = n2 * sigmoid(n2 @ wgate + bgate)
  k_gemm<2><<<dim3(6, 32, 1), 256, 0, stream>>>(
      n2buf, WT + oWG, 768, 768, 0, 0,
      gated, nullptr, nullptr, n2buf, nullptr, bgate);

  // U = gated @ w1
  k_gemm<0><<<dim3(16, 32, 1), 256, 0, stream>>>(
      gated, WT + oW1, 2048, 768, 0, 0,
      Ubuf, nullptr, nullptr, nullptr, nullptr, nullptr);

  // t = silu(U) * (gated @ w3)
  k_gemm<3><<<dim3(16, 32, 1), 256, 0, stream>>>(
      gated, WT + oW3, 2048, 768, 0, 0,
      tbuf, nullptr, nullptr, Ubuf, nullptr, nullptr);

  // out_hidden = h2 + (t @ w2) * active   (f32, straight to d_out)
  k_gemm<1><<<dim3(6, 32, 1), 256, 0, stream>>>(
      tbuf, WT + oW2, 768, 2048, 0, 0,
      nullptr, out_hidden, h2, nullptr, actF, nullptr);

  (void)in_sizes; (void)n_in; (void)out_size; (void)ws_size;
}